// Round 3
// baseline (57.855 us; speedup 1.0000x reference)
//
#include <hip/hip_runtime.h>

namespace {

constexpr int Bn = 16, An = 3, Cn = 80, NTGT = 200;
constexpr unsigned CH = 85;
constexpr unsigned S0 = 80, S1 = 40, S2 = 20;

constexpr unsigned L0 = (unsigned)Bn * An * S0 * S0 * CH;  // 26,112,000 floats
constexpr unsigned L1 = (unsigned)Bn * An * S1 * S1 * CH;  //  6,528,000
constexpr unsigned L2 = (unsigned)Bn * An * S2 * S2 * CH;  //  1,632,000
constexpr unsigned F0 = L0 / 4, F1 = L1 / 4, F2 = L2 / 4;  // float4 counts

constexpr unsigned BLOCK = 256;
// Segment block counts, proportional to F0:F1:F2 (16.3 float4/thread each).
constexpr unsigned B0 = 1560, B1 = 390, B2 = 98;
constexpr unsigned NBLK = B0 + B1 + B2;                    // 2048

constexpr float WO0 = 1.0f / ((float)Bn * An * S0 * S0);
constexpr float WO1 = 1.0f / ((float)Bn * An * S1 * S1);
constexpr float WO2 = 1.0f / ((float)Bn * An * S2 * S2);
constexpr float WC0 = WO0 / (float)Cn;
constexpr float WC1 = WO1 / (float)Cn;
constexpr float WC2 = WO2 / (float)Cn;

// Branch-free BCE(z=0) contribution of one float4 whose first element has
// channel c0 (mod 85). softplus via -|x| form: 2 transcendentals/element.
__device__ __forceinline__ void proc4(const float4 v, unsigned c0,
                                      float wo, float wc,
                                      float& accO, float& accC)
{
    float vals[4] = {v.x, v.y, v.z, v.w};
    #pragma unroll
    for (int k = 0; k < 4; ++k) {
        unsigned c = c0 + (unsigned)k;
        c = (c >= CH) ? c - CH : c;
        float x  = vals[k];
        float e  = __expf(-fabsf(x));
        float sp = fmaxf(x, 0.0f) + __logf(1.0f + e);
        accO += ((c == 4u) ? wo : 0.0f) * sp;
        accC += ((c >  4u) ? wc : 0.0f) * sp;
    }
}

__global__ __launch_bounds__(BLOCK) void yolo_sum_kernel(
    const float* __restrict__ p0, const float* __restrict__ p1,
    const float* __restrict__ p2, float2* __restrict__ part)
{
    unsigned bid = blockIdx.x;
    const float4* P; unsigned n4, seg0; float wo, wc;
    if (bid < B0) {
        P = (const float4*)p0; n4 = F0; seg0 = bid;           wo = WO0; wc = WC0;
    } else if (bid < B0 + B1) {
        P = (const float4*)p1; n4 = F1; seg0 = bid - B0;      wo = WO1; wc = WC1;
    } else {
        P = (const float4*)p2; n4 = F2; seg0 = bid - B0 - B1; wo = WO2; wc = WC2;
    }
    unsigned nthB = (bid < B0) ? B0 : (bid < B0 + B1) ? B1 : B2;
    unsigned nth  = nthB * BLOCK;                 // threads in this segment
    unsigned i    = seg0 * BLOCK + threadIdx.x;   // my float4 cursor

    // running channel of element 4*i (mod 85), advanced incrementally
    unsigned c0   = (i * 4u) % CH;
    unsigned step = (nth * 4u) % CH;              // advance per grid-stride

    float accO = 0.0f, accC = 0.0f;

    // main loop: 8 independent float4 loads in flight
    while (i + 7u * nth < n4) {
        float4 v[8];
        #pragma unroll
        for (int k = 0; k < 8; ++k) v[k] = P[i + (unsigned)k * nth];
        unsigned c = c0;
        #pragma unroll
        for (int k = 0; k < 8; ++k) {
            proc4(v[k], c, wo, wc, accO, accC);
            c += step;
            c = (c >= CH) ? c - CH : c;
        }
        i  += 8u * nth;
        c0 = c;
    }
    // tail (< 8 strided iterations)
    for (; i < n4; i += nth) {
        proc4(P[i], c0, wo, wc, accO, accC);
        c0 += step;
        c0 = (c0 >= CH) ? c0 - CH : c0;
    }

    #pragma unroll
    for (int off = 32; off > 0; off >>= 1) {
        accO += __shfl_down(accO, off);
        accC += __shfl_down(accC, off);
    }
    __shared__ float sO[4], sC[4];
    int lane = threadIdx.x & 63, wv = threadIdx.x >> 6;
    if (lane == 0) { sO[wv] = accO; sC[wv] = accC; }
    __syncthreads();
    if (threadIdx.x == 0)
        part[blockIdx.x] = make_float2(sO[0] + sO[1] + sO[2] + sO[3],
                                       sC[0] + sC[1] + sC[2] + sC[3]);
}

// Single-block correction: dedup targets per cell via packed u32 keys and
// subtract the l*z terms at the <=200 hot cells per scale.
__global__ __launch_bounds__(BLOCK) void yolo_corr_kernel(
    const float* __restrict__ p0, const float* __restrict__ p1,
    const float* __restrict__ p2, const float* __restrict__ tgt,
    float2* __restrict__ part)
{
    __shared__ unsigned keyO[NTGT], keyC[NTGT];

    int t = threadIdx.x;
    float fb = 0.f, fc = 0.f, fx = 0.f, fy = 0.f;
    bool valid = false;
    if (t < NTGT) {
        fb = tgt[t * 6 + 0];
        fc = tgt[t * 6 + 1];
        fx = tgt[t * 6 + 2];
        fy = tgt[t * 6 + 3];
        valid = (fc < (float)Cn);
    }
    int b  = valid ? (int)fb : 0;
    int cl = valid ? (int)fc : 0;

    const float* preds[3] = {p0, p1, p2};
    const int    SS[3]    = {(int)S0, (int)S1, (int)S2};
    const float  WOs[3]   = {WO0, WO1, WO2};
    const float  WCs[3]   = {WC0, WC1, WC2};

    float corrO = 0.0f, corrC = 0.0f;

    for (int s = 0; s < 3; ++s) {
        int W = SS[s];
        unsigned myO = 0x80000000u | (unsigned)t;  // unique, matches nothing
        unsigned myC = myO;
        float vObj = 0.f, vCls = 0.f;
        if (t < NTGT && valid) {
            int gx = min((int)floorf(fx * (float)W), W - 1);
            int gy = min((int)floorf(fy * (float)W), W - 1);
            myO = ((unsigned)b << 14) | ((unsigned)gy << 7) | (unsigned)gx;
            myC = (myO << 7) | (unsigned)cl;
            // issue scattered HBM loads NOW; latency hides under dedup loop
            const float* P = preds[s];
            unsigned cell = ((unsigned)b * 3u * (unsigned)W + (unsigned)gy)
                            * (unsigned)W + (unsigned)gx;   // anchor a=0
            vObj = P[cell * CH + 4u];
            vCls = P[cell * CH + 5u + (unsigned)cl];
        }
        if (t < NTGT) { keyO[t] = myO; keyC[t] = myC; }
        __syncthreads();

        bool uo = true, uc = true;
        int lim = (t < NTGT) ? t : 0;
        #pragma unroll 4
        for (int j = 0; j < lim; ++j) {
            unsigned ko = keyO[j], kc = keyC[j];
            uo = uo && (ko != myO);
            uc = uc && (kc != myC);
        }
        if (t < NTGT && valid) {
            if (uo) corrO -= vObj * WOs[s];
            if (uc) corrC -= vCls * WCs[s];
        }
        __syncthreads();
    }

    #pragma unroll
    for (int off = 32; off > 0; off >>= 1) {
        corrO += __shfl_down(corrO, off);
        corrC += __shfl_down(corrC, off);
    }
    __shared__ float rO[4], rC[4];
    int lane = threadIdx.x & 63, wv = threadIdx.x >> 6;
    if (lane == 0) { rO[wv] = corrO; rC[wv] = corrC; }
    __syncthreads();
    if (threadIdx.x == 0)
        part[NBLK] = make_float2(rO[0] + rO[1] + rO[2] + rO[3],
                                 rC[0] + rC[1] + rC[2] + rC[3]);
}

__global__ __launch_bounds__(BLOCK) void yolo_final_kernel(
    const float2* __restrict__ part, float* __restrict__ out)
{
    float o = 0.0f, c = 0.0f;
    for (unsigned i = threadIdx.x; i < NBLK + 1u; i += BLOCK) {
        float2 p = part[i];
        o += p.x; c += p.y;
    }
    #pragma unroll
    for (int off = 32; off > 0; off >>= 1) {
        o += __shfl_down(o, off);
        c += __shfl_down(c, off);
    }
    __shared__ float sO[4], sC[4];
    int lane = threadIdx.x & 63, wv = threadIdx.x >> 6;
    if (lane == 0) { sO[wv] = o; sC[wv] = c; }
    __syncthreads();
    if (threadIdx.x == 0) {
        float obj = sO[0] + sO[1] + sO[2] + sO[3];
        float cls = sC[0] + sC[1] + sC[2] + sC[3];
        out[0] = obj + 0.5f * cls;   // BOX_W*0 + OBJ_W*obj + CLS_W*cls
        out[1] = 0.0f;               // total_box
        out[2] = obj;
        out[3] = cls;
    }
}

}  // namespace

extern "C" void kernel_launch(void* const* d_in, const int* in_sizes, int n_in,
                              void* d_out, int out_size, void* d_ws, size_t ws_size,
                              hipStream_t stream)
{
    const float* p0  = (const float*)d_in[0];
    const float* p1  = (const float*)d_in[1];
    const float* p2  = (const float*)d_in[2];
    const float* tgt = (const float*)d_in[3];
    float* out = (float*)d_out;
    float2* part = (float2*)d_ws;   // [0..NBLK-1] sum partials, [NBLK] corr

    yolo_sum_kernel  <<<NBLK, BLOCK, 0, stream>>>(p0, p1, p2, part);
    yolo_corr_kernel <<<1,    BLOCK, 0, stream>>>(p0, p1, p2, tgt, part);
    yolo_final_kernel<<<1,    BLOCK, 0, stream>>>(part, out);
}

// Round 4
// 52.909 us; speedup vs baseline: 1.0935x; 1.0935x over previous
//
#include <hip/hip_runtime.h>

namespace {

constexpr int Bn = 16, An = 3, Cn = 80, NTGT = 200;
constexpr unsigned CH = 85;
constexpr unsigned S0 = 80, S1 = 40, S2 = 20;

constexpr unsigned F0 = 16u * 3u * 80u * 80u * 85u / 4u;   // 6,528,000 float4
constexpr unsigned F1 = 16u * 3u * 40u * 40u * 85u / 4u;   // 1,632,000
constexpr unsigned F2 = 16u * 3u * 20u * 20u * 85u / 4u;   //   408,000

constexpr unsigned BLOCK = 256;
// seg0/seg1: exact division into per-block contiguous chunks of R rounds.
constexpr unsigned B0 = 1500, R0 = 17;  // 1500*17*256 = 6,528,000 exactly
constexpr unsigned B1 = 375,  R1 = 17;  //  375*17*256 = 1,632,000 exactly
constexpr unsigned B2 = 128;            // predicated chunks of CHUNK2
constexpr unsigned CHUNK2 = 3188;       // 128*3188 = 408,064 >= F2
constexpr unsigned NBLK = B0 + B1 + B2; // 2003 (<=2048: one resident wave of blocks)

constexpr float WO0 = 1.0f / (48.0f * 80.0f * 80.0f);
constexpr float WO1 = 1.0f / (48.0f * 40.0f * 40.0f);
constexpr float WO2 = 1.0f / (48.0f * 20.0f * 20.0f);
constexpr float WC0 = WO0 / 80.0f;
constexpr float WC1 = WO1 / 80.0f;
constexpr float WC2 = WO2 / 80.0f;

// Transcendental-free softplus: sp(x) = max(x,0) + log1p(e^{-|x|}).
// e^{-t}: s = t*log2e; n=floor(s); 2^{-frac} deg-3 poly (rel err <= 4.5e-4);
// log1p(u): deg-7 Horner in z=2u-1 (err <= 3e-5). All FMA-pipe, no v_exp/v_log.
__device__ __forceinline__ float softplus_fast(float x) {
    float t = fabsf(x);
    float s = fminf(t * 1.44269504f, 30.0f);
    int   n = (int)s;                       // trunc == floor (s >= 0)
    float f = s - (float)n;
    float d = f - 0.5f;
    float q = fmaf(-0.03924558f, d, 0.16986903f);
    q = fmaf(q, d, -0.49012907f);
    q = fmaf(q, d, 0.70710678f);            // ~= 2^{-f}
    float e2 = __int_as_float((127 - n) << 23);
    float u  = q * e2;                      // ~= e^{-t} in (0,1]
    float z  = fmaf(2.0f, u, -1.0f);
    float p  = fmaf(6.53211e-5f, z, -2.28624e-4f);
    p = fmaf(p, z,  8.23045e-4f);
    p = fmaf(p, z, -3.08641975e-3f);
    p = fmaf(p, z,  1.23456790e-2f);
    p = fmaf(p, z, -5.55555556e-2f);
    p = fmaf(p, z,  3.33333333e-1f);
    p = fmaf(p, z,  4.05465108e-1f);        // ~= log1p(u)
    return fmaxf(x, 0.0f) + p;
}

// Branch-free accumulate of one float4 (unweighted; weights applied at end).
__device__ __forceinline__ void proc4(const float4 v, unsigned c0,
                                      float& accO, float& accC)
{
    float vals[4] = {v.x, v.y, v.z, v.w};
    #pragma unroll
    for (int k = 0; k < 4; ++k) {
        unsigned c = c0 + (unsigned)k;
        c = (c >= CH) ? c - CH : c;
        float sp = softplus_fast(vals[k]);
        accO += (c == 4u) ? sp : 0.0f;
        accC += (c >  4u) ? sp : 0.0f;
    }
}

__global__ __launch_bounds__(BLOCK) void yolo_sum_kernel(
    const float* __restrict__ p0, const float* __restrict__ p1,
    const float* __restrict__ p2, float2* __restrict__ part)
{
    unsigned bid = blockIdx.x;
    float accO = 0.0f, accC = 0.0f;
    float wo, wc;

    if (bid < B0 + B1) {
        // clean path: 17 rounds, no predication, contiguous 69.6 KB chunk
        const float4* P;
        unsigned i;
        if (bid < B0) { P = (const float4*)p0; i = bid * (R0 * BLOCK) + threadIdx.x; wo = WO0; wc = WC0; }
        else          { P = (const float4*)p1; i = (bid - B0) * (R1 * BLOCK) + threadIdx.x; wo = WO1; wc = WC1; }
        unsigned c0 = (i * 4u) % CH;

        #pragma unroll 1
        for (int rb = 0; rb < 4; ++rb) {    // 4 batches x 4 rounds
            float4 v[4];
            #pragma unroll
            for (int k = 0; k < 4; ++k) v[k] = P[i + (unsigned)k * BLOCK];
            #pragma unroll
            for (int k = 0; k < 4; ++k) {
                proc4(v[k], c0, accO, accC);
                c0 += 4u; c0 = (c0 >= CH) ? c0 - CH : c0;
            }
            i += 4u * BLOCK;
        }
        proc4(P[i], c0, accO, accC);        // round 17
    } else {
        // seg2: predicated chunk
        const float4* P = (const float4*)p2;
        unsigned cbase = (bid - B0 - B1) * CHUNK2;
        unsigned end   = min(cbase + CHUNK2, F2);
        unsigned i     = cbase + threadIdx.x;
        unsigned c0    = (i * 4u) % CH;
        wo = WO2; wc = WC2;

        #pragma unroll 1
        for (int rb = 0; rb < 4; ++rb) {    // 13 rounds: 3x4 + 1
            float4 v[4] = {{0,0,0,0},{0,0,0,0},{0,0,0,0},{0,0,0,0}};
            int nk = (rb < 3) ? 4 : 1;
            for (int k = 0; k < nk; ++k) {
                unsigned ii = i + (unsigned)k * BLOCK;
                if (ii < end) v[k] = P[ii];
            }
            for (int k = 0; k < nk; ++k) {
                bool inb = (i + (unsigned)k * BLOCK) < end;
                proc4(v[k], inb ? c0 : 0u, accO, accC);  // c in 0..3 -> zero contrib
                c0 += 4u; c0 = (c0 >= CH) ? c0 - CH : c0;
            }
            i += 4u * BLOCK;
        }
    }

    #pragma unroll
    for (int off = 32; off > 0; off >>= 1) {
        accO += __shfl_down(accO, off);
        accC += __shfl_down(accC, off);
    }
    __shared__ float sO[4], sC[4];
    int lane = threadIdx.x & 63, wv = threadIdx.x >> 6;
    if (lane == 0) { sO[wv] = accO; sC[wv] = accC; }
    __syncthreads();
    if (threadIdx.x == 0)
        part[blockIdx.x] = make_float2(wo * (sO[0] + sO[1] + sO[2] + sO[3]),
                                       wc * (sC[0] + sC[1] + sC[2] + sC[3]));
}

// Merged correction + final: dedup targets per cell (packed u32 keys),
// subtract l*z at the <=200 hot cells per scale, add all block partials,
// write the 4 outputs. Single block.
__global__ __launch_bounds__(BLOCK) void yolo_corr_final_kernel(
    const float* __restrict__ p0, const float* __restrict__ p1,
    const float* __restrict__ p2, const float* __restrict__ tgt,
    const float2* __restrict__ part, float* __restrict__ out)
{
    __shared__ unsigned keyO[NTGT], keyC[NTGT];

    int t = threadIdx.x;
    float fb = 0.f, fc = 0.f, fx = 0.f, fy = 0.f;
    bool valid = false;
    if (t < NTGT) {
        fb = tgt[t * 6 + 0];
        fc = tgt[t * 6 + 1];
        fx = tgt[t * 6 + 2];
        fy = tgt[t * 6 + 3];
        valid = (fc < (float)Cn);
    }
    int b  = valid ? (int)fb : 0;
    int cl = valid ? (int)fc : 0;

    const float* preds[3] = {p0, p1, p2};
    const int    SS[3]    = {(int)S0, (int)S1, (int)S2};
    const float  WOs[3]   = {WO0, WO1, WO2};
    const float  WCs[3]   = {WC0, WC1, WC2};

    float accO = 0.0f, accC = 0.0f;

    for (int s = 0; s < 3; ++s) {
        int W = SS[s];
        unsigned myO = 0x80000000u | (unsigned)t;  // unique sentinel
        unsigned myC = myO;
        float vObj = 0.f, vCls = 0.f;
        if (t < NTGT && valid) {
            int gx = min((int)floorf(fx * (float)W), W - 1);
            int gy = min((int)floorf(fy * (float)W), W - 1);
            myO = ((unsigned)b << 14) | ((unsigned)gy << 7) | (unsigned)gx;
            myC = (myO << 7) | (unsigned)cl;
            const float* P = preds[s];
            unsigned cell = ((unsigned)b * 3u * (unsigned)W + (unsigned)gy)
                            * (unsigned)W + (unsigned)gx;   // anchor a=0
            vObj = P[cell * CH + 4u];
            vCls = P[cell * CH + 5u + (unsigned)cl];
        }
        if (t < NTGT) { keyO[t] = myO; keyC[t] = myC; }
        __syncthreads();

        bool uo = true, uc = true;
        int lim = (t < NTGT) ? t : 0;
        #pragma unroll 4
        for (int j = 0; j < lim; ++j) {
            unsigned ko = keyO[j], kc = keyC[j];
            uo = uo && (ko != myO);
            uc = uc && (kc != myC);
        }
        if (t < NTGT && valid) {
            if (uo) accO -= vObj * WOs[s];
            if (uc) accC -= vCls * WCs[s];
        }
        __syncthreads();
    }

    // add the grid partials
    for (unsigned i = threadIdx.x; i < NBLK; i += BLOCK) {
        float2 pp = part[i];
        accO += pp.x; accC += pp.y;
    }

    #pragma unroll
    for (int off = 32; off > 0; off >>= 1) {
        accO += __shfl_down(accO, off);
        accC += __shfl_down(accC, off);
    }
    __shared__ float rO[4], rC[4];
    int lane = threadIdx.x & 63, wv = threadIdx.x >> 6;
    if (lane == 0) { rO[wv] = accO; rC[wv] = accC; }
    __syncthreads();
    if (threadIdx.x == 0) {
        float obj = rO[0] + rO[1] + rO[2] + rO[3];
        float cls = rC[0] + rC[1] + rC[2] + rC[3];
        out[0] = obj + 0.5f * cls;   // BOX_W*0 + OBJ_W*obj + CLS_W*cls
        out[1] = 0.0f;               // total_box
        out[2] = obj;
        out[3] = cls;
    }
}

}  // namespace

extern "C" void kernel_launch(void* const* d_in, const int* in_sizes, int n_in,
                              void* d_out, int out_size, void* d_ws, size_t ws_size,
                              hipStream_t stream)
{
    const float* p0  = (const float*)d_in[0];
    const float* p1  = (const float*)d_in[1];
    const float* p2  = (const float*)d_in[2];
    const float* tgt = (const float*)d_in[3];
    float* out = (float*)d_out;
    float2* part = (float2*)d_ws;   // NBLK partials

    yolo_sum_kernel       <<<NBLK, BLOCK, 0, stream>>>(p0, p1, p2, part);
    yolo_corr_final_kernel<<<1,    BLOCK, 0, stream>>>(p0, p1, p2, tgt, part, out);
}